// Round 11
// baseline (621.820 us; speedup 1.0000x reference)
//
#include <hip/hip_runtime.h>
#include <math.h>

// Problem constants (match reference setup_inputs)
constexpr int NA = 4096, NP = 100000, E_AP = 500000, E_PA = 500000;
constexpr int D = 128, DFF = 2048, NOUT = 16, IN_A = 128, IN_P = 256;

typedef __attribute__((ext_vector_type(8))) short bf16x8;
typedef __attribute__((ext_vector_type(4))) float f32x4;
typedef unsigned int u32;

// round-to-nearest-even f32 -> bf16 bits
__device__ __forceinline__ ushort f2b(float x) {
    union { float f; unsigned u; } v; v.f = x;
    unsigned r = v.u + 0x7fff + ((v.u >> 16) & 1);
    return (ushort)(r >> 16);
}
__device__ __forceinline__ float b2f(ushort h) {
    union { unsigned u; float f; } v; v.u = (unsigned)h << 16;
    return v.f;
}
__device__ __forceinline__ u32 fbits(float x) {
    union { float f; u32 u; } v; v.f = x; return v.u;
}

// 8x f32 -> bf16x8 via packed HW convert (RNE, matches f2b on finite vals)
__device__ __forceinline__ bf16x8 cvtfrag(float4 a, float4 b) {
    union { u32 w[4]; bf16x8 v; } r;
    asm("v_cvt_pk_bf16_f32 %0, %1, %2" : "=v"(r.w[0]) : "v"(a.x), "v"(a.y));
    asm("v_cvt_pk_bf16_f32 %0, %1, %2" : "=v"(r.w[1]) : "v"(a.z), "v"(a.w));
    asm("v_cvt_pk_bf16_f32 %0, %1, %2" : "=v"(r.w[2]) : "v"(b.x), "v"(b.y));
    asm("v_cvt_pk_bf16_f32 %0, %1, %2" : "=v"(r.w[3]) : "v"(b.z), "v"(b.w));
    return r.v;
}

#define GLL(gp, lp) __builtin_amdgcn_global_load_lds( \
    (const __attribute__((address_space(1))) u32*)(gp), \
    (__attribute__((address_space(3))) u32*)(lp), 16, 0, 0)

#define MFMA16(a, b, c) __builtin_amdgcn_mfma_f32_16x16x32_bf16((a), (b), (c), 0, 0, 0)

// ---------------------------------------------------------------------------
// bf16 MFMA GEMM:  out = act(A @ B^T + bias)
// R6 structure: BK=128 groups, LDS 1040B-stride payload blocks, M-tile 64.
// R8 epilogue: bf16-out path repacks acc through LDS ([64][134] ushort) and
// stores 4x dwordx4 per thread instead of 32 scalar ushort stores.
__global__ __launch_bounds__(256) void gemm_bf16(
    const ushort* __restrict__ Abf, const float* __restrict__ Af32, int lda,
    const ushort* __restrict__ B, int ldb,
    const float* __restrict__ bias,
    float* __restrict__ outf, ushort* __restrict__ outh, int ldc,
    int M, int N, int K, int act)
{
    __shared__ uint8_t lds[(16 + 32) * 1040];   // A:16 blocks, B:32 blocks
    uint8_t* sAb = lds;                          // block (g,s) at (g*4+s)*1040
    uint8_t* sBb = lds + 16 * 1040;

    const int wave = threadIdx.x >> 6;
    const int lane = threadIdx.x & 63;
    const int l16 = lane & 15, quad = lane >> 4;
    const int row0 = blockIdx.y * 64;
    const int col0 = blockIdx.x * 128;
    const int wrg = (wave >> 1) * 2;             // A row-group base (2 groups/wave)
    const int wc0 = (wave & 1) * 64;
    const int nz = gridDim.z;
    const int ksub = K / nz;
    const int kbeg = blockIdx.z * ksub;
    const int kgrps = ksub >> 7;                 // BK=128 groups

    f32x4 acc[2][4] = {};

    const int sr = lane & 15, sc = lane >> 4;
    const int arow = min(row0 + lane, M - 1);    // A: thread 'lane' owns one row
    const int ag = lane >> 4;
    uint8_t* adst = sAb + (ag * 4 + wave) * 1040 + sr * 16;

    for (int grp = 0; grp < kgrps; ++grp) {
        const int kg = kbeg + grp * 128;
        if (grp) __syncthreads();
        #pragma unroll
        for (int gg = 0; gg < 2; ++gg) {
            int g = wave * 2 + gg;
            const ushort* bp = B + (long)(col0 + g * 16 + sr) * ldb + kg + sc * 8;
            #pragma unroll
            for (int s = 0; s < 4; ++s)
                GLL(bp + s * 32, sBb + (g * 4 + s) * 1040);
        }
        if (Af32) {
            const float* ap = Af32 + (long)arow * lda + kg + wave * 32;
            #pragma unroll
            for (int q = 0; q < 4; ++q) {
                float4 f0 = *(const float4*)(ap + q * 8);
                float4 f1 = *(const float4*)(ap + q * 8 + 4);
                *(bf16x8*)(adst + q * 256) = cvtfrag(f0, f1);
            }
        } else {
            const ushort* ap = Abf + (long)arow * lda + kg + wave * 32;
            #pragma unroll
            for (int q = 0; q < 4; ++q)
                *(bf16x8*)(adst + q * 256) = *(const bf16x8*)(ap + q * 8);
        }
        __syncthreads();
        #pragma unroll
        for (int s = 0; s < 4; ++s) {
            bf16x8 af[2], bfr[4];
            #pragma unroll
            for (int i = 0; i < 2; ++i)
                af[i] = *(const bf16x8*)(sAb + ((wrg + i) * 4 + s) * 1040 + lane * 16);
            #pragma unroll
            for (int j = 0; j < 4; ++j)
                bfr[j] = *(const bf16x8*)(sBb + (((wc0 >> 4) + j) * 4 + s) * 1040 + lane * 16);
            #pragma unroll
            for (int i = 0; i < 2; ++i)
                #pragma unroll
                for (int j = 0; j < 4; ++j)
                    acc[i][j] = MFMA16(af[i], bfr[j], acc[i][j]);
        }
    }

    if (outh && nz == 1) {
        // ---- wide-store epilogue: acc -> LDS [64][134] -> dwordx4 stores
        __syncthreads();                      // K-loop LDS dead
        ushort* sC = (ushort*)lds;
        #pragma unroll
        for (int i = 0; i < 2; ++i) {
            #pragma unroll
            for (int r = 0; r < 4; ++r) {
                int lrow = wrg * 16 + i * 16 + quad * 4 + r;
                #pragma unroll
                for (int j = 0; j < 4; ++j) {
                    int lcol = wc0 + j * 16 + l16;
                    float v = acc[i][j][r] + (bias ? bias[col0 + lcol] : 0.f);
                    if (act) v = fmaxf(v, 0.f);
                    sC[lrow * 134 + lcol] = f2b(v);
                }
            }
        }
        __syncthreads();
        int rr = threadIdx.x >> 2, qq = threadIdx.x & 3;
        int grow = row0 + rr;
        if (grow < M) {
            const ushort* src = sC + rr * 134 + qq * 32;
            ushort* dst = outh + (long)grow * ldc + col0 + qq * 32;
            #pragma unroll
            for (int k = 0; k < 4; ++k)
                *(bf16x8*)(dst + k * 8) = *(const bf16x8*)(src + k * 8);
        }
        return;
    }

    #pragma unroll
    for (int i = 0; i < 2; ++i) {
        #pragma unroll
        for (int r = 0; r < 4; ++r) {
            int row = row0 + wrg * 16 + i * 16 + quad * 4 + r;
            if (row >= M) continue;
            #pragma unroll
            for (int j = 0; j < 4; ++j) {
                int col = col0 + wc0 + j * 16 + l16;
                if (nz > 1) {
                    atomicAdd(&outf[(long)row * ldc + col], acc[i][j][r]);
                } else {
                    float v = acc[i][j][r] + (bias ? bias[col] : 0.f);
                    if (act) v = fmaxf(v, 0.f);
                    if (outf) outf[(long)row * ldc + col] = v;
                }
            }
        }
    }
}

// ---------------------------------------------------------------------------
// Fused FFN: out += relu(x1 @ W1^T + b1) @ W2^T  (fp32 atomic accumulate).
__global__ __launch_bounds__(256) void ffn_fused(
    const ushort* __restrict__ x1b,   // [8192,128] bf16
    const ushort* __restrict__ W1b,   // [2048,128] bf16
    const ushort* __restrict__ W2b,   // [128,2048] bf16
    const float* __restrict__ b1,     // [2048] fp32
    float* __restrict__ outf)         // [8192,128] fp32, pre-zeroed
{
    __shared__ uint8_t lds[56 * 1040];
    uint8_t* sX  = lds;
    uint8_t* sW1 = lds + 16 * 1040;
    uint8_t* sW2 = lds + 32 * 1040;
    uint8_t* sH  = lds + 48 * 1040;

    const int wave = threadIdx.x >> 6;
    const int lane = threadIdx.x & 63;
    const int l16 = lane & 15, quad = lane >> 4;
    const int sr = lane & 15, sc = lane >> 4;
    const int row0 = blockIdx.x * 64;
    const int dbeg = blockIdx.y * 512;

    const int xg = wave >> 1;
    const int ch = wave & 1;

    {
        const ushort* xp = x1b + (long)(row0 + wave * 16 + sr) * 128 + sc * 8;
        #pragma unroll
        for (int s = 0; s < 4; ++s)
            GLL(xp + s * 32, sX + (wave * 4 + s) * 1040);
    }

    f32x4 acc2[2][4] = {};

    for (int c = 0; c < 8; ++c) {
        const int kc = dbeg + c * 64;
        {
            const ushort* w1p = W1b + (long)(kc + wave * 16 + sr) * 128 + sc * 8;
            #pragma unroll
            for (int s = 0; s < 4; ++s)
                GLL(w1p + s * 32, sW1 + (wave * 4 + s) * 1040);
            #pragma unroll
            for (int gg = 0; gg < 2; ++gg) {
                int cg = wave * 2 + gg;
                const ushort* w2p = W2b + (long)(cg * 16 + sr) * 2048 + kc + sc * 8;
                #pragma unroll
                for (int s2 = 0; s2 < 2; ++s2)
                    GLL(w2p + s2 * 32, sW2 + (cg * 2 + s2) * 1040);
            }
        }
        __syncthreads();

        f32x4 acc1[2][2] = {};
        #pragma unroll
        for (int s = 0; s < 4; ++s) {
            bf16x8 a0 = *(const bf16x8*)(sX + ((xg * 2 + 0) * 4 + s) * 1040 + lane * 16);
            bf16x8 a1 = *(const bf16x8*)(sX + ((xg * 2 + 1) * 4 + s) * 1040 + lane * 16);
            bf16x8 w0 = *(const bf16x8*)(sW1 + ((ch * 2 + 0) * 4 + s) * 1040 + lane * 16);
            bf16x8 w1 = *(const bf16x8*)(sW1 + ((ch * 2 + 1) * 4 + s) * 1040 + lane * 16);
            acc1[0][0] = MFMA16(a0, w0, acc1[0][0]);
            acc1[0][1] = MFMA16(a0, w1, acc1[0][1]);
            acc1[1][0] = MFMA16(a1, w0, acc1[1][0]);
            acc1[1][1] = MFMA16(a1, w1, acc1[1][1]);
        }
        float bb0 = b1[kc + ch * 32 + l16];
        float bb1 = b1[kc + ch * 32 + 16 + l16];
        #pragma unroll
        for (int i = 0; i < 2; ++i) {
            uint8_t* hb = sH + ((xg * 2 + i) * 2 + ch) * 1040;
            #pragma unroll
            for (int j = 0; j < 2; ++j) {
                float bb = j ? bb1 : bb0;
                int q = ((j * 16 + l16) >> 3) & 3;
                int byo = (l16 & 7) * 2;
                #pragma unroll
                for (int r = 0; r < 4; ++r) {
                    float v = fmaxf(acc1[i][j][r] + bb, 0.f);
                    *(ushort*)(hb + q * 256 + (quad * 4 + r) * 16 + byo) = f2b(v);
                }
            }
        }
        __syncthreads();

        #pragma unroll
        for (int s2 = 0; s2 < 2; ++s2) {
            bf16x8 h0 = *(const bf16x8*)(sH + ((xg * 2 + 0) * 2 + s2) * 1040 + lane * 16);
            bf16x8 h1 = *(const bf16x8*)(sH + ((xg * 2 + 1) * 2 + s2) * 1040 + lane * 16);
            #pragma unroll
            for (int j2 = 0; j2 < 4; ++j2) {
                bf16x8 wb = *(const bf16x8*)(sW2 + ((ch * 4 + j2) * 2 + s2) * 1040 + lane * 16);
                acc2[0][j2] = MFMA16(h0, wb, acc2[0][j2]);
                acc2[1][j2] = MFMA16(h1, wb, acc2[1][j2]);
            }
        }
        __syncthreads();
    }

    #pragma unroll
    for (int i = 0; i < 2; ++i)
        #pragma unroll
        for (int r = 0; r < 4; ++r) {
            int row = row0 + xg * 32 + i * 16 + quad * 4 + r;
            #pragma unroll
            for (int j2 = 0; j2 < 4; ++j2) {
                int col = ch * 64 + j2 * 16 + l16;
                atomicAdd(&outf[(long)row * 128 + col], acc2[i][j2][r]);
            }
        }
}

// ---------------------------------------------------------------------------
// Wf_l = Wo_l @ Wv_l (bf16 out),  beff_l = bo_l + Wo_l @ bv_l (fp32)
__global__ __launch_bounds__(256) void fuse_weights(
    const float* __restrict__ Wv0, const float* __restrict__ bv0,
    const float* __restrict__ Wo0, const float* __restrict__ bo0,
    const float* __restrict__ Wv1, const float* __restrict__ bv1,
    const float* __restrict__ Wo1, const float* __restrict__ bo1,
    const float* __restrict__ Wv2, const float* __restrict__ bv2,
    const float* __restrict__ Wo2, const float* __restrict__ bo2,
    ushort* __restrict__ Wfb, float* __restrict__ beff)
{
    int blk = blockIdx.x;
    if (blk >= 192) {
        int l = blk - 192;
        const float* bv = l == 0 ? bv0 : (l == 1 ? bv1 : bv2);
        const float* Wo = l == 0 ? Wo0 : (l == 1 ? Wo1 : Wo2);
        const float* bo = l == 0 ? bo0 : (l == 1 ? bo1 : bo2);
        if (threadIdx.x < 128) {
            int r = threadIdx.x;
            float acc = bo[r];
            #pragma unroll 8
            for (int j = 0; j < 128; ++j) acc += Wo[r * 128 + j] * bv[j];
            beff[l * 128 + r] = acc;
        }
        return;
    }
    int l = blk >> 6;
    const float* Wv = l == 0 ? Wv0 : (l == 1 ? Wv1 : Wv2);
    const float* Wo = l == 0 ? Wo0 : (l == 1 ? Wo1 : Wo2);
    int r = (blk & 63) * 2 + (threadIdx.x >> 7);
    int c = threadIdx.x & 127;
    float acc = 0.f;
    #pragma unroll 8
    for (int j = 0; j < 128; ++j)
        acc += Wo[r * 128 + j] * Wv[j * 128 + c];
    Wfb[l * 16384 + r * 128 + c] = f2b(acc);
}

// ---------------------------------------------------------------------------
// CSR build (merged A/P pipelines via blockIdx.y).
// hist returns the per-edge local offset (wait hidden by TLP); fill is
// atomic-free (slot = off[dst] + local) -- R9, verified -90us.
__global__ void hist2(const int* __restrict__ dA, int* __restrict__ cA, int* __restrict__ lA,
                      const int* __restrict__ dP, int* __restrict__ cP, int* __restrict__ lP,
                      int E)
{
    int e = blockIdx.x * 256 + threadIdx.x;
    if (e >= E) return;
    if (blockIdx.y == 0) lA[e] = atomicAdd(&cA[dA[e]], 1);
    else                 lP[e] = atomicAdd(&cP[dP[e]], 1);
}

__global__ __launch_bounds__(256) void scan_local2(
    const int* __restrict__ inA, int* __restrict__ outA, int* __restrict__ bsumA, int nA,
    const int* __restrict__ inP, int* __restrict__ outP, int* __restrict__ bsumP, int nP)
{
    const int* in  = blockIdx.y ? inP  : inA;
    int* out       = blockIdx.y ? outP : outA;
    int* bsum      = blockIdx.y ? bsumP : bsumA;
    int n          = blockIdx.y ? nP : nA;
    __shared__ int wsum[4];
    int t = threadIdx.x;
    int base = blockIdx.x * 1024 + t * 4;
    int v0 = (base + 0 < n) ? in[base + 0] : 0;
    int v1 = (base + 1 < n) ? in[base + 1] : 0;
    int v2 = (base + 2 < n) ? in[base + 2] : 0;
    int v3 = (base + 3 < n) ? in[base + 3] : 0;
    int tsum = v0 + v1 + v2 + v3;
    int lane = t & 63;
    int x = tsum;
    #pragma unroll
    for (int o = 1; o < 64; o <<= 1) {
        int y = __shfl_up(x, o, 64);
        if (lane >= o) x += y;
    }
    int wid = t >> 6;
    if (lane == 63) wsum[wid] = x;
    __syncthreads();
    int woff = 0;
    #pragma unroll
    for (int ww = 0; ww < 3; ++ww) if (ww < wid) woff += wsum[ww];
    int excl = x - tsum + woff;
    if (base + 0 < n) out[base + 0] = excl;
    if (base + 1 < n) out[base + 1] = excl + v0;
    if (base + 2 < n) out[base + 2] = excl + v0 + v1;
    if (base + 3 < n) out[base + 3] = excl + v0 + v1 + v2;
    if (bsum && t == 255) bsum[blockIdx.x] = excl + tsum;
}

__global__ void scan_add2(int* __restrict__ offA, const int* __restrict__ bA, int nA,
                          int* __restrict__ offP, const int* __restrict__ bP, int nP)
{
    int* off       = blockIdx.y ? offP : offA;
    const int* bofs= blockIdx.y ? bP   : bA;
    int n          = blockIdx.y ? nP : nA;
    int i = blockIdx.x * 256 + threadIdx.x;
    if (i < n) off[i] += bofs[i >> 10];
}

__global__ void fill2(const int* __restrict__ sA, const int* __restrict__ dA,
                      const int* __restrict__ oA, const int* __restrict__ lA,
                      int* __restrict__ eA,
                      const int* __restrict__ sP, const int* __restrict__ dP,
                      const int* __restrict__ oP, const int* __restrict__ lP,
                      int* __restrict__ eP, int E)
{
    int e = blockIdx.x * 256 + threadIdx.x;
    if (e >= E) return;
    if (blockIdx.y == 0) eA[oA[dA[e]] + lA[e]] = sA[e];
    else                 eP[oP[dP[e]] + lP[e]] = sP[e];
}

// ---------------------------------------------------------------------------
// gather + mean only (bf16 in -> bf16 out). One 32-lane group per dst row.
__global__ __launch_bounds__(256) void gather_mean(
    const ushort* __restrict__ z, const int* __restrict__ off,
    const int* __restrict__ cnt, const int* __restrict__ esrc,
    ushort* __restrict__ outh, int R)
{
    int grp = threadIdx.x >> 5;
    int tg  = threadIdx.x & 31;
    int row = blockIdx.x * 8 + grp;
    if (row >= R) return;
    int e0 = off[row], deg = cnt[row];
    int eend = e0 + deg;
    float a0 = 0.f, a1 = 0.f, a2 = 0.f, a3 = 0.f;
    int e = e0;
    for (; e + 4 <= eend; e += 4) {
        int s0 = esrc[e], s1 = esrc[e + 1], s2 = esrc[e + 2], s3 = esrc[e + 3];
        ushort4 v0 = ((const ushort4*)(z + (long)s0 * 128))[tg];
        ushort4 v1 = ((const ushort4*)(z + (long)s1 * 128))[tg];
        ushort4 v2 = ((const ushort4*)(z + (long)s2 * 128))[tg];
        ushort4 v3 = ((const ushort4*)(z + (long)s3 * 128))[tg];
        a0 += b2f(v0.x) + b2f(v1.x) + b2f(v2.x) + b2f(v3.x);
        a1 += b2f(v0.y) + b2f(v1.y) + b2f(v2.y) + b2f(v3.y);
        a2 += b2f(v0.z) + b2f(v1.z) + b2f(v2.z) + b2f(v3.z);
        a3 += b2f(v0.w) + b2f(v1.w) + b2f(v2.w) + b2f(v3.w);
    }
    for (; e < eend; ++e) {
        int s = esrc[e];
        ushort4 v = ((const ushort4*)(z + (long)s * 128))[tg];
        a0 += b2f(v.x); a1 += b2f(v.y); a2 += b2f(v.z); a3 += b2f(v.w);
    }
    float inv = 1.f / fmaxf((float)deg, 1.f);
    ushort4 h4 = {f2b(a0 * inv), f2b(a1 * inv), f2b(a2 * inv), f2b(a3 * inv)};
    ((ushort4*)(outh + (long)row * 128))[tg] = h4;
}

// ---------------------------------------------------------------------------
// Fused gather(bf16) + mean + residual(bf16) + LayerNorm -> bf16 out.
__global__ __launch_bounds__(256) void gather_mean_ln(
    const ushort* __restrict__ z, const int* __restrict__ off,
    const int* __restrict__ cnt, const int* __restrict__ esrc,
    const ushort* __restrict__ base, const float* __restrict__ g,
    const float* __restrict__ b, ushort* __restrict__ outh, int R)
{
    int grp = threadIdx.x >> 5;
    int tg  = threadIdx.x & 31;
    int row = blockIdx.x * 8 + grp;
    if (row >= R) return;
    int e0 = off[row], deg = cnt[row];
    int eend = e0 + deg;
    float a0 = 0.f, a1 = 0.f, a2 = 0.f, a3 = 0.f;
    int e = e0;
    for (; e + 4 <= eend; e += 4) {
        int s0 = esrc[e], s1 = esrc[e + 1], s2 = esrc[e + 2], s3 = esrc[e + 3];
        ushort4 v0 = ((const ushort4*)(z + (long)s0 * 128))[tg];
        ushort4 v1 = ((const ushort4*)(z + (long)s1 * 128))[tg];
        ushort4 v2 = ((const ushort4*)(z + (long)s2 * 128))[tg];
        ushort4 v3 = ((const ushort4*)(z + (long)s3 * 128))[tg];
        a0 += b2f(v0.x) + b2f(v1.x) + b2f(v2.x) + b2f(v3.x);
        a1 += b2f(v0.y) + b2f(v1.y) + b2f(v2.y) + b2f(v3.y);
        a2 += b2f(v0.z) + b2f(v1.z) + b2f(v2.z) + b2f(v3.z);
        a3 += b2f(v0.w) + b2f(v1.w) + b2f(v2.w) + b2f(v3.w);
    }
    for (; e < eend; ++e) {
        int s = esrc[e];
        ushort4 v = ((const ushort4*)(z + (long)s * 128))[tg];
        a0 += b2f(v.x); a1 += b2f(v.y); a2 += b2f(v.z); a3 += b2f(v.w);
    }
    float inv = 1.f / fmaxf((float)deg, 1.f);
    ushort4 bs = ((const ushort4*)(base + (long)row * 128))[tg];
    float x0 = a0 * inv + b2f(bs.x), x1 = a1 * inv + b2f(bs.y);
    float x2 = a2 * inv + b2f(bs.z), x3 = a3 * inv + b2f(bs.w);
    float s1 = x0 + x1 + x2 + x3;
    #pragma unroll
    for (int o = 1; o < 32; o <<= 1) s1 += __shfl_xor(s1, o, 64);
    float mu = s1 * (1.f / 128.f);
    float d0 = x0 - mu, d1 = x1 - mu, d2 = x2 - mu, d3 = x3 - mu;
    float s2 = d0 * d0 + d1 * d1 + d2 * d2 + d3 * d3;
    #pragma unroll
    for (int o = 1; o < 32; o <<= 1) s2 += __shfl_xor(s2, o, 64);
    float rstd = rsqrtf(s2 * (1.f / 128.f) + 1e-5f);
    float4 gv = ((const float4*)g)[tg];
    float4 bv = ((const float4*)b)[tg];
    ushort4 h4;
    h4.x = f2b(d0 * rstd * gv.x + bv.x);
    h4.y = f2b(d1 * rstd * gv.y + bv.y);
    h4.z = f2b(d2 * rstd * gv.z + bv.z);
    h4.w = f2b(d3 * rstd * gv.w + bv.w);
    ((ushort4*)(outh + (long)row * 128))[tg] = h4;
}

// ---------------------------------------------------------------------------
// out = LN(a + bias + base)*g + b ; base either fp32 (basef) or bf16 (baseh).
__global__ __launch_bounds__(128) void mean_add_ln(
    const float* __restrict__ a, const float* __restrict__ bias,
    const float* __restrict__ basef, const ushort* __restrict__ baseh,
    const float* __restrict__ g, const float* __restrict__ b,
    float* __restrict__ outf, ushort* __restrict__ outh, int out_ld, int R)
{
    int row = blockIdx.x;
    if (row >= R) return;
    int d = threadIdx.x;
    float x = a[(long)row * 128 + d];
    if (bias) x += bias[d];
    if (basef) x += basef[(long)row * 128 + d];
    if (baseh) x += b2f(baseh[(long)row * 128 + d]);

    __shared__ float red[4];
    float s = x;
    #pragma unroll
    for (int o = 32; o >= 1; o >>= 1) s += __shfl_xor(s, o, 64);
    if ((d & 63) == 0) red[d >> 6] = s;
    __syncthreads();
    float mu = (red[0] + red[1]) * (1.f / 128.f);
    float dx = x - mu;
    float s2 = dx * dx;
    #pragma unroll
    for (int o = 32; o >= 1; o >>= 1) s2 += __shfl_xor(s2, o, 64);
    if ((d & 63) == 0) red[2 + (d >> 6)] = s2;
    __syncthreads();
    float var = (red[2] + red[3]) * (1.f / 128.f);
    float v = dx * rsqrtf(var + 1e-5f) * g[d] + b[d];
    if (outf) outf[(long)row * out_ld + d] = v;
    if (outh) outh[(long)row * out_ld + d] = f2b(v);
}

// ---------------------------------------------------------------------------
struct CvtArgs { const float* in[6]; ushort* out[6]; int n4[6]; };
__global__ void cvt_multi(CvtArgs a)
{
    int j = blockIdx.y;
    int i = blockIdx.x * 256 + threadIdx.x;
    if (i >= a.n4[j]) return;
    float4 v = ((const float4*)a.in[j])[i];
    ushort4 o;
    o.x = f2b(v.x); o.y = f2b(v.y); o.z = f2b(v.z); o.w = f2b(v.w);
    ((ushort4*)a.out[j])[i] = o;
}

// ---------------------------------------------------------------------------
// Flash attention. R11: ks=2 (R9's better split: fewer per-block fixed costs
// + less partial traffic) combined with R10's K-via-global_load_lds into
// linear 64B-row sK (saves the K reg round-trip VALU; read pattern
// (t*16+l16)*32+quad*8 ushorts distributes 8 lanes/4-bank group = bank
// floor). sV/sP swizzled as R5 (verified conflict-free).
__global__ __launch_bounds__(256) void flash_attn(
    const ushort* __restrict__ qkvb,
    float* __restrict__ opart, float* __restrict__ lpart_g)
{
    const int qt = blockIdx.x;
    const int mh = blockIdx.y;
    const int ks = blockIdx.z;
    const int m = mh >> 2, h = mh & 3;
    const int wave = threadIdx.x >> 6;
    const int lane = threadIdx.x & 63;
    const int l16 = lane & 15, quad = lane >> 4;

    __shared__ ushort sK[2][64 * 32];   // 8KB, linear 64B rows (GLL dest)
    __shared__ u32    sV[2][32 * 32];   // 8KB, swizzled
    __shared__ u32    sP[4][16 * 32];   // 8KB, swizzled

    const int q0 = qt * 64 + wave * 16;
    const float qs = 0.17677669529663687f * 1.4426950408889634f;
    bf16x8 qf;
    {
        bf16x8 qraw = *(const bf16x8*)(qkvb + ((long)(q0 + l16) * 2 + m) * 384 + h * 32 + quad * 8);
        #pragma unroll
        for (int j = 0; j < 8; ++j)
            qf[j] = (short)f2b(b2f((ushort)qraw[j]) * qs);
    }

    f32x4 oacc0 = {0.f, 0.f, 0.f, 0.f};
    f32x4 oacc1 = {0.f, 0.f, 0.f, 0.f};
    float lp = 0.f;

    const int kbeg = ks * (NA / 2);
    // K staging via GLL: wave w stages keys w*16+(lane>>2), seg lane&3
    // (dest = wave-uniform base + lane*16B, matching linear [key][seg]).
    const int kkey = wave * 16 + (lane >> 2), kseg = lane & 3;
    const ushort* kgsrc = qkvb + ((long)((kbeg + kkey) * 2 + m)) * 384 + 128 + h * 32 + kseg * 8;
    // V staging (register path: needs 16-bit keypair interleave)
    const int vkp  = threadIdx.x & 31, vdc  = (threadIdx.x >> 5) * 4;
    const ushort* vbase = qkvb + ((long)((kbeg + vkp * 2) * 2 + m)) * 384 + 256 + h * 32 + vdc;
    int vwo[4];
    #pragma unroll
    for (int i = 0; i < 4; ++i)
        vwo[i] = (vdc + i) * 32 + ((((vkp >> 2) ^ ((vdc + i) & 7)) << 2) | (vkp & 3));

    // prologue: stage tile 0
    GLL(kgsrc, &sK[0][wave * 512]);
    ushort4 v0r = *(const ushort4*)(vbase);
    ushort4 v1r = *(const ushort4*)(vbase + 768);
    sV[0][vwo[0]] = (u32)v0r.x | ((u32)v1r.x << 16);
    sV[0][vwo[1]] = (u32)v0r.y | ((u32)v1r.y << 16);
    sV[0][vwo[2]] = (u32)v0r.z | ((u32)v1r.z << 16);
    sV[0][vwo[3]] = (u32)v0r.w | ((u32)v1r.w << 16);
    __syncthreads();

    int cur = 0;
    for (int kt = 0; kt < 32; ++kt) {
        const bool more = (kt + 1) < 32;
        const int nxt = cur ^ 1;
        if (more) {   // issue next-tile loads; latency hides under QK+PV
            long off = (long)(kt + 1) * 64 * 768;
            GLL(kgsrc + off, &sK[nxt][wave * 512]);
            v0r = *(const ushort4*)(vbase + off);
            v1r = *(const ushort4*)(vbase + off + 768);
        }

        #pragma unroll
        for (int t = 0; t < 4; ++t) {
            bf16x8 kf = *(const bf16x8*)(&sK[cur][(t * 16 + l16) * 32 + quad * 8]);
            f32x4 s = {0.f, 0.f, 0.f, 0.f};
            s = MFMA16(kf, qf, s);
            float p0 = exp2f(s[0]), p1 = exp2f(s[1]);
            float p2 = exp2f(s[2]), p3 = exp2f(s[3]);
            lp += (p0 + p1) + (p2 + p3);
            u32 lo = __builtin_amdgcn_perm(fbits(p1), fbits(p0), 0x07060302u);
            u32 hi = __builtin_amdgcn_perm(fbits(p3), fbits(p2), 0x07060302u);
            u32* dst = &sP[wave][l16 * 32 +
                                 ((((t * 2 + (quad >> 1)) ^ (l16 & 7)) << 2) | ((quad & 1) * 2))];
            dst[0] = lo; dst[1] = hi;
        }
        #pragma unroll
        for (int c = 0; c < 2; ++c) {
            const int gp = ((c * 4 + quad) ^ (l16 & 7)) << 2;
            bf16x8 pf  = *(const bf16x8*)(&sP[wave][l16 * 32 + gp]);
            bf16x8 vf0 = *(const bf16x8*)(&sV[cur][l16 * 32 + gp]);
            bf16x8 vf1 = *(const bf16x8*)(&sV[cur][(16 + l16) * 32 + gp]);
            oacc0 = MFMA16(pf, vf0, oacc0);
            oacc1 = MFMA16(pf, vf1, oacc1);
        }

        if (more) {   // land V regs into other buffer; barrier drains K GLL
            sV[nxt][vwo[0]] = (u32)v0r.x | ((u32)v1r.x << 16);
            sV[nxt][vwo[1]] = (u32)v0r.y | ((u32)v1r.y << 16);
            sV[nxt][vwo[2]] = (u32)v0r.z | ((u32)v1r.z << 16);
            sV[nxt][vwo[3]] = (u32)v0r.w | ((u32)v1r.w << 16);
            __syncthreads();
            cur = nxt;
        }
    }

    lp += __shfl_xor(lp, 16, 64);
    lp += __shfl_xor(lp, 32, 64);
    if (quad == 0)
        lpart_g[(long)(mh * 2 + ks) * NA + q0 + l16] = lp;

    #pragma unroll
    for (int r = 0; r < 4; ++r) {
        int qr = q0 + quad * 4 + r;
        long ob = ((long)(mh * 2 + ks) * NA + qr) * 32;
        opart[ob + l16]      = oacc0[r];
        opart[ob + 16 + l16] = oacc1[r];
    }
}

__global__ void attn_combine(const float* __restrict__ opart,
                             const float* __restrict__ lpart,
                             ushort* __restrict__ ctxb)
{
    int idx = blockIdx.x * 256 + threadIdx.x;   // 8*4096*32
    int d = idx & 31;
    int row = idx >> 5;
    int mh = row >> 12, qrow = row & 4095;
    float o = 0.f, l = 0.f;
    #pragma unroll
    for (int ks = 0; ks < 2; ++ks) {
        long rb = (long)(mh * 2 + ks) * NA + qrow;
        o += opart[rb * 32 + d];
        l += lpart[rb];
    }
    int m = mh >> 2, h = mh & 3;
    ctxb[((long)qrow * 2 + m) * 128 + h * 32 + d] = f2b(o / l);
}

// out[a][o] = sum_d 0.5*(x2[2a][d]+x2[2a+1][d]) * Wc[o][d] + bc[o]
__global__ void classify_kernel(const float* __restrict__ x2,
                                const float* __restrict__ Wc,
                                const float* __restrict__ bc,
                                float* __restrict__ out)
{
    int idx = blockIdx.x * 256 + threadIdx.x;
    int a2 = idx >> 4, o = idx & 15;
    const float* r0 = x2 + (long)(a2 * 2) * 128;
    const float* r1 = r0 + 128;
    const float* w = Wc + o * 128;
    float acc = bc[o];
    #pragma unroll 4
    for (int dd = 0; dd < 128; ++dd) acc += 0.5f * (r0[dd] + r1[dd]) * w[dd];
    out[idx] = acc;
}

// ---------------------------------------------------------------------------
static void bgemm(hipStream_t st, const ushort* Abf, const float* Af32, int lda,
                  const ushort* B, int ldb,
                  const float* bias, float* outf, ushort* outh, int ldc,
                  int M, int N, int K, int act = 0, int ksplit = 1)
{
    dim3 grid(N / 128, (M + 63) / 64, ksplit);
    gemm_bf16<<<grid, 256, 0, st>>>(Abf, Af32, lda, B, ldb, bias, outf, outh,
                                    ldc, M, N, K, act);
}

extern "C" void kernel_launch(void* const* d_in, const int* in_sizes, int n_in,
                              void* d_out, int out_size, void* d_ws, size_t ws_size,
                              hipStream_t stream)
{
    const float* x_author = (const float*)d_in[0];
    const float* x_paper  = (const float*)d_in[1];
    const int*   src_ap   = (const int*)d_in[2];
    const int*   dst_ap   = (const int*)d_in[3];
    const int*   src_pa   = (const int*)d_in[4];
    const int*   dst_pa   = (const int*)d_in[5];
    const float* pa_W = (const float*)d_in[6];   const float* pa_b = (const float*)d_in[7];
    const float* pp_W = (const float*)d_in[8];   const float* pp_b = (const float*)d_in[9];
    const float* f_Wqkv = (const float*)d_in[10]; const float* f_bqkv = (const float*)d_in[11];
    const float* f_Wo = (const float*)d_in[12];  const float* f_bo = (const float*)d_in[13];
    const float* f_W1 = (const float*)d_in[14];  const float* f_b1 = (const float*)d_in[15];
    const float* f_W2 = (const float*)d_in[16];  const float* f_b2 = (const float*)d_in[17];
    const float* f_g1 = (const float*)d_in[18];  const float* f_bt1 = (const float*)d_in[19];
    const float* f_g2 = (const float*)d_in[20];  const float* f_bt2 = (const float*)d_in[21];
    const float* cls_W = (const float*)d_in[22]; const float* cls_b = (const float*)d_in[23];
    const float* l0_Wv = (const float*)d_in[24]; const float* l0_bv = (const float*)d_in[25];
    const float* l0_Wo = (const float*)d_in[26]; const float* l0_bo = (const float*)d_in[27];
    const float* l0_g  = (const float*)d_in[28]; const float* l0_b  = (const float*)d_in[29];
    const float* l1_Wv = (const float*)d_in[30]; const float* l1_bv = (const float*)d_in[31];
    const float* l1_Wo = (const float*)d_in[32]; const float* l1_bo = (const float*)d_in[33];
    const float* l1_g  = (const float*)d_in[34]; const float* l1_b  = (const float*)d_in[35];
    const float* l2_Wv = (const float*)d_in[36]; const float* l2_bv = (const float*)d_in[37];
    const float* l2_Wo = (const float*)d_in[38]; const float* l2_bo = (const float*)d_in[39];
    const float* l2_g  = (const float*)d_in[40]; const float* l2_b  = (const float*)d_in[41];

    // ---- workspace carve (bytes), overlays by liveness:
    uint8_t* w = (uint8_t*)d_ws;
    ushort* TB  = (ushort*)(w + 0);            // t bf16 [NP,128] 25.6MB
    float*  OPART = (float*)(w + 26214400);    // attn partials 8MB (ks=2)
    float*  LPART = (float*)(w + 43515904);    // l partials 256KB
    int*   LOC_A  = (int*)(w + 44040192);      // per-edge local offs 2MB (CSR phase)
    int*   LOC_P  = (int*)(w + 46140416);      // 2MB (CSR phase)
    ushort* HPB = (ushort*)(w + 61440000);     // [NP,128] bf16 25.6MB
    ushort* ZB  = (ushort*)(w + 87040000);     // z bf16 [NA,128] 1.05MB
    uint8_t* p2 = w + 102400000;               // phase-2 small tensors
    ushort* QKVB = (ushort*)(p2 + 0);          // [8192,384] bf16 6.29MB
    ushort* CTXB = (ushort*)(p2 + 6291456);    // [8192,128] bf16 2.1MB
    float*  TMP  = (float*)(p2 + 8388608);     // [8192,128] fp32 4.2MB
    float*  X1   = (float*)(p2 + 12582912);    // [8192,128] fp32
    ushort* X1B  = (ushort*)(p2 + 16777216);   // [8192,128] bf16
    float*  TMP2 = (float*)(p2 + 18874368);    // [8192,128] fp32
    float*  X2   = (float*)(p2 + 23068672);    // [8192,128] fp32
    uint8_t* tail = p2 + 27262976;             // persistent
    ushort* STKB  = (ushort*)(tail + 4194304); // [8192,128] bf16 ld 256 layout
    ushort* HAB   = (ushort*)(tail + 6291456); // [NA,128] bf16 1.05MB
    ushort* GMA   = (ushort*)(tail + 7340032); // gathered mean bf16 [NA,128]
    ushort* WFB   = (ushort*)(tail + 8388608); // 3x[128,128] bf16 98KB
    ushort* PAWB  = (ushort*)(tail + 8486912); // [128,128]
    ushort* PPWB  = (ushort*)(tail + 8519680); // [128,256]
    ushort* WQKVB = (ushort*)(tail + 8585216); // [384,128]
    ushort* WOB   = (ushort*)(tail + 8683520); // [128,128]
    ushort* W1B   = (ushort*)(tail + 8716288); // [2048,128]
    ushort* W2B   = (ushort*)(tail + 9240576); // [128,2048]
    float*  BEFF  = (float*)(tail + 9764864);  // 3x[128] fp32
    int*   CNT_A  = (int*)(tail + 9766400);
    int*   OFF_A  = (int*)(tail + 9782784);
    int*   CNT_P  = (int*)(tail + 9815552);
    int*   OFF_P  = (int*)(tail + 10215552);
    int*   ESRC_PA= (int*)(tail + 11015552);
    int*   ESRC_AP= (int*)(tail + 13015552);
    int*   BSUM_A = (int*)(tail + 15015552);
    int*   BSUM_P = (int*)(tail + 15016576);
    float* TMPA   = (float*)(tail + 15017984); // [NA,128] fp32 2.1MB

    // ---- convert weights to bf16 (activations convert in-GEMM)
    CvtArgs ca;
    ca.in[0] = pa_W;   ca.out[0] = PAWB;  ca.n4[0] = D * IN_A / 4;
    ca.in[1] = pp_W;   ca.out[1] = PPWB;  ca.n4[1] = D * IN_P / 4;
    ca.in[2] = f_Wqkv; ca.out[2] = WQKVB; ca.n4[2] = 3 * D * D / 4;
    ca.in[3] = f_Wo;   ca.out[3] = WOB;   ca.n4[3] = D * D / 4;
    ca.in[4] = f_W1;   ca.out[4] = W1B;   ca.n4[4] = DFF * D / 4;
    ca.in[5] = f_W2;   ca.out[5] = W2B;   ca.n4[5] = D * DFF / 4;
    cvt_multi<<<dim3((DFF * D / 4 + 255) / 256, 6), 256, 0, stream>>>(ca);

    fuse_weights<<<195, 256, 0, stream>>>(l0_Wv, l0_bv, l0_Wo, l0_bo,
                                          l1_Wv, l1_bv, l1_Wo, l1_bo,
                                          l2_Wv, l2_bv, l2_Wo, l2_bo, WFB, BEFF);

    // ---- CSR builds, merged A/P pipelines; hist returns per-edge local
    // offset so fill needs no atomic.
    hipMemsetAsync(CNT_A, 0, (size_t)NA * 4, stream);
    hipMemsetAsync(CNT_P, 0, (size_t)NP * 4, stream);
    const int nbA = (NA + 1023) / 1024, nbP = (NP + 1023) / 1024;
    hist2<<<dim3((E_PA + 255) / 256, 2), 256, 0, stream>>>(
        dst_pa, CNT_A, LOC_A, dst_ap, CNT_P, LOC_P, E_PA);
    scan_local2<<<dim3(nbP, 2), 256, 0, stream>>>(CNT_A, OFF_A, BSUM_A, NA,
                                                  CNT_P, OFF_P, BSUM_P, NP);
    scan_local2<<<dim3(1, 2), 256, 0, stream>>>(BSUM_A, BSUM_A, nullptr, nbA,
                                                BSUM_P, BSUM_P, nullptr, nbP);
    scan_add2<<<dim3((NP + 255) / 256, 2), 256, 0, stream>>>(OFF_A, BSUM_A, NA,
                                                             OFF_P, BSUM_P, NP);
    fill2<<<dim3((E_PA + 255) / 256, 2), 256, 0, stream>>>(
        src_pa, dst_pa, OFF_A, LOC_A, ESRC_PA,
        src_ap, dst_ap, OFF_P, LOC_P, ESRC_AP, E_PA);

    // ---- node projections
    bgemm(stream, nullptr, x_author, IN_A, PAWB, IN_A, pa_b, nullptr, HAB, D, NA, D, IN_A);
    bgemm(stream, nullptr, x_paper,  IN_P, PPWB, IN_P, pp_b, nullptr, HPB, D, NP, D, IN_P);

    // ---- metapath 0 (gather-first; K=128 -> bias in-GEMM)
    gather_mean<<<(NA + 7) / 8, 256, 0, stream>>>(HPB, OFF_A, CNT_A, ESRC_PA, GMA, NA);
    bgemm(stream, GMA, nullptr, D, WFB, D, BEFF, TMPA, nullptr, D, NA, D, D);
    mean_add_ln<<<NA, 128, 0, stream>>>(TMPA, nullptr, nullptr, HAB, l0_g, l0_b,
                                        nullptr, STKB, 256, NA);

    // ---- metapath 1 step 1: project (NA rows, cheap), gather into papers
    bgemm(stream, HAB, nullptr, D, WFB + 16384, D, BEFF + 128, nullptr, ZB, D, NA, D, D);
    gather_mean_ln<<<(NP + 7) / 8, 256, 0, stream>>>(
        ZB, OFF_P, CNT_P, ESRC_AP, HPB, l1_g, l1_b, TB, NP);

    // ---- metapath 1 step 2 (gather-first again)
    gather_mean<<<(NA + 7) / 8, 256, 0, stream>>>(TB, OFF_A, CNT_A, ESRC_PA, GMA, NA);
    bgemm(stream, GMA, nullptr, D, WFB + 32768, D, BEFF + 256, TMPA, nullptr, D, NA, D, D);
    mean_add_ln<<<NA, 128, 0, stream>>>(TMPA, nullptr, nullptr, HAB, l2_g, l2_b,
                                        nullptr, STKB + 128, 256, NA);

    // ---- fusion transformer
    bgemm(stream, STKB, nullptr, D, WQKVB, D, f_bqkv, nullptr, QKVB, 3 * D, 2 * NA, 3 * D, D);
    flash_attn<<<dim3(NA / 64, 8, 2), 256, 0, stream>>>(QKVB, OPART, LPART);
    attn_combine<<<8 * NA * 32 / 256, 256, 0, stream>>>(OPART, LPART, CTXB);

    // x1 = LN(stk + ctx@Wo^T + bo): K=128 -> direct with bias in-GEMM
    bgemm(stream, CTXB, nullptr, D, WOB, D, f_bo, TMP, nullptr, D, 2 * NA, D, D);
    mean_add_ln<<<2 * NA, 128, 0, stream>>>(TMP, nullptr, nullptr, STKB, f_g1, f_bt1,
                                            X1, X1B, 128, 2 * NA);

    // FFN fused: x2_pre = relu(x1@W1^T+b1)@W2^T (atomic fp32), then LN
    hipMemsetAsync(TMP2, 0, (size_t)2 * NA * D * 4, stream);
    ffn_fused<<<dim3(2 * NA / 64, 4), 256, 0, stream>>>(X1B, W1B, W2B, f_b1, TMP2);
    mean_add_ln<<<2 * NA, 128, 0, stream>>>(TMP2, f_b2, X1, nullptr, f_g2, f_bt2,
                                            X2, nullptr, 128, 2 * NA);

    // ---- mean over metapaths + classifier (fp32)
    classify_kernel<<<(NA * NOUT) / 256, 256, 0, stream>>>(X2, cls_W, cls_b, (float*)d_out);
}

// Round 12
// 611.013 us; speedup vs baseline: 1.0177x; 1.0177x over previous
//
#include <hip/hip_runtime.h>
#include <math.h>

// Problem constants (match reference setup_inputs)
constexpr int NA = 4096, NP = 100000, E_AP = 500000, E_PA = 500000;
constexpr int D = 128, DFF = 2048, NOUT = 16, IN_A = 128, IN_P = 256;

typedef __attribute__((ext_vector_type(8))) short bf16x8;
typedef __attribute__((ext_vector_type(4))) float f32x4;
typedef unsigned int u32;

// round-to-nearest-even f32 -> bf16 bits
__device__ __forceinline__ ushort f2b(float x) {
    union { float f; unsigned u; } v; v.f = x;
    unsigned r = v.u + 0x7fff + ((v.u >> 16) & 1);
    return (ushort)(r >> 16);
}
__device__ __forceinline__ float b2f(ushort h) {
    union { unsigned u; float f; } v; v.u = (unsigned)h << 16;
    return v.f;
}
__device__ __forceinline__ u32 fbits(float x) {
    union { float f; u32 u; } v; v.f = x; return v.u;
}

// 8x f32 -> bf16x8 via packed HW convert (RNE, matches f2b on finite vals)
__device__ __forceinline__ bf16x8 cvtfrag(float4 a, float4 b) {
    union { u32 w[4]; bf16x8 v; } r;
    asm("v_cvt_pk_bf16_f32 %0, %1, %2" : "=v"(r.w[0]) : "v"(a.x), "v"(a.y));
    asm("v_cvt_pk_bf16_f32 %0, %1, %2" : "=v"(r.w[1]) : "v"(a.z), "v"(a.w));
    asm("v_cvt_pk_bf16_f32 %0, %1, %2" : "=v"(r.w[2]) : "v"(b.x), "v"(b.y));
    asm("v_cvt_pk_bf16_f32 %0, %1, %2" : "=v"(r.w[3]) : "v"(b.z), "v"(b.w));
    return r.v;
}

#define GLL(gp, lp) __builtin_amdgcn_global_load_lds( \
    (const __attribute__((address_space(1))) u32*)(gp), \
    (__attribute__((address_space(3))) u32*)(lp), 16, 0, 0)

#define MFMA16(a, b, c) __builtin_amdgcn_mfma_f32_16x16x32_bf16((a), (b), (c), 0, 0, 0)

// ---------------------------------------------------------------------------
// bf16 MFMA GEMM:  out = act(A @ B^T + bias)
// R6 structure: BK=128 groups, LDS 1040B-stride payload blocks, M-tile 64.
// R8 epilogue: bf16-out path repacks acc through LDS ([64][134] ushort) and
// stores 4x dwordx4 per thread instead of 32 scalar ushort stores.
__global__ __launch_bounds__(256) void gemm_bf16(
    const ushort* __restrict__ Abf, const float* __restrict__ Af32, int lda,
    const ushort* __restrict__ B, int ldb,
    const float* __restrict__ bias,
    float* __restrict__ outf, ushort* __restrict__ outh, int ldc,
    int M, int N, int K, int act)
{
    __shared__ uint8_t lds[(16 + 32) * 1040];   // A:16 blocks, B:32 blocks
    uint8_t* sAb = lds;                          // block (g,s) at (g*4+s)*1040
    uint8_t* sBb = lds + 16 * 1040;

    const int wave = threadIdx.x >> 6;
    const int lane = threadIdx.x & 63;
    const int l16 = lane & 15, quad = lane >> 4;
    const int row0 = blockIdx.y * 64;
    const int col0 = blockIdx.x * 128;
    const int wrg = (wave >> 1) * 2;             // A row-group base (2 groups/wave)
    const int wc0 = (wave & 1) * 64;
    const int nz = gridDim.z;
    const int ksub = K / nz;
    const int kbeg = blockIdx.z * ksub;
    const int kgrps = ksub >> 7;                 // BK=128 groups

    f32x4 acc[2][4] = {};

    const int sr = lane & 15, sc = lane >> 4;
    const int arow = min(row0 + lane, M - 1);    // A: thread 'lane' owns one row
    const int ag = lane >> 4;
    uint8_t* adst = sAb + (ag * 4 + wave) * 1040 + sr * 16;

    for (int grp = 0; grp < kgrps; ++grp) {
        const int kg = kbeg + grp * 128;
        if (grp) __syncthreads();
        #pragma unroll
        for (int gg = 0; gg < 2; ++gg) {
            int g = wave * 2 + gg;
            const ushort* bp = B + (long)(col0 + g * 16 + sr) * ldb + kg + sc * 8;
            #pragma unroll
            for (int s = 0; s < 4; ++s)
                GLL(bp + s * 32, sBb + (g * 4 + s) * 1040);
        }
        if (Af32) {
            const float* ap = Af32 + (long)arow * lda + kg + wave * 32;
            #pragma unroll
            for (int q = 0; q < 4; ++q) {
                float4 f0 = *(const float4*)(ap + q * 8);
                float4 f1 = *(const float4*)(ap + q * 8 + 4);
                *(bf16x8*)(adst + q * 256) = cvtfrag(f0, f1);
            }
        } else {
            const ushort* ap = Abf + (long)arow * lda + kg + wave * 32;
            #pragma unroll
            for (int q = 0; q < 4; ++q)
                *(bf16x8*)(adst + q * 256) = *(const bf16x8*)(ap + q * 8);
        }
        __syncthreads();
        #pragma unroll
        for (int s = 0; s < 4; ++s) {
            bf16x8 af[2], bfr[4];
            #pragma unroll
            for (int i = 0; i < 2; ++i)
                af[i] = *(const bf16x8*)(sAb + ((wrg + i) * 4 + s) * 1040 + lane * 16);
            #pragma unroll
            for (int j = 0; j < 4; ++j)
                bfr[j] = *(const bf16x8*)(sBb + (((wc0 >> 4) + j) * 4 + s) * 1040 + lane * 16);
            #pragma unroll
            for (int i = 0; i < 2; ++i)
                #pragma unroll
                for (int j = 0; j < 4; ++j)
                    acc[i][j] = MFMA16(af[i], bfr[j], acc[i][j]);
        }
    }

    if (outh && nz == 1) {
        // ---- wide-store epilogue: acc -> LDS [64][134] -> dwordx4 stores
        __syncthreads();                      // K-loop LDS dead
        ushort* sC = (ushort*)lds;
        #pragma unroll
        for (int i = 0; i < 2; ++i) {
            #pragma unroll
            for (int r = 0; r < 4; ++r) {
                int lrow = wrg * 16 + i * 16 + quad * 4 + r;
                #pragma unroll
                for (int j = 0; j < 4; ++j) {
                    int lcol = wc0 + j * 16 + l16;
                    float v = acc[i][j][r] + (bias ? bias[col0 + lcol] : 0.f);
                    if (act) v = fmaxf(v, 0.f);
                    sC[lrow * 134 + lcol] = f2b(v);
                }
            }
        }
        __syncthreads();
        int rr = threadIdx.x >> 2, qq = threadIdx.x & 3;
        int grow = row0 + rr;
        if (grow < M) {
            const ushort* src = sC + rr * 134 + qq * 32;
            ushort* dst = outh + (long)grow * ldc + col0 + qq * 32;
            #pragma unroll
            for (int k = 0; k < 4; ++k)
                *(bf16x8*)(dst + k * 8) = *(const bf16x8*)(src + k * 8);
        }
        return;
    }

    #pragma unroll
    for (int i = 0; i < 2; ++i) {
        #pragma unroll
        for (int r = 0; r < 4; ++r) {
            int row = row0 + wrg * 16 + i * 16 + quad * 4 + r;
            if (row >= M) continue;
            #pragma unroll
            for (int j = 0; j < 4; ++j) {
                int col = col0 + wc0 + j * 16 + l16;
                if (nz > 1) {
                    atomicAdd(&outf[(long)row * ldc + col], acc[i][j][r]);
                } else {
                    float v = acc[i][j][r] + (bias ? bias[col] : 0.f);
                    if (act) v = fmaxf(v, 0.f);
                    if (outf) outf[(long)row * ldc + col] = v;
                }
            }
        }
    }
}

// ---------------------------------------------------------------------------
// Fused FFN: out += relu(x1 @ W1^T + b1) @ W2^T  (fp32 atomic accumulate).
__global__ __launch_bounds__(256) void ffn_fused(
    const ushort* __restrict__ x1b,   // [8192,128] bf16
    const ushort* __restrict__ W1b,   // [2048,128] bf16
    const ushort* __restrict__ W2b,   // [128,2048] bf16
    const float* __restrict__ b1,     // [2048] fp32
    float* __restrict__ outf)         // [8192,128] fp32, pre-zeroed
{
    __shared__ uint8_t lds[56 * 1040];
    uint8_t* sX  = lds;
    uint8_t* sW1 = lds + 16 * 1040;
    uint8_t* sW2 = lds + 32 * 1040;
    uint8_t* sH  = lds + 48 * 1040;

    const int wave = threadIdx.x >> 6;
    const int lane = threadIdx.x & 63;
    const int l16 = lane & 15, quad = lane >> 4;
    const int sr = lane & 15, sc = lane >> 4;
    const int row0 = blockIdx.x * 64;
    const int dbeg = blockIdx.y * 512;

    const int xg = wave >> 1;
    const int ch = wave & 1;

    {
        const ushort* xp = x1b + (long)(row0 + wave * 16 + sr) * 128 + sc * 8;
        #pragma unroll
        for (int s = 0; s < 4; ++s)
            GLL(xp + s * 32, sX + (wave * 4 + s) * 1040);
    }

    f32x4 acc2[2][4] = {};

    for (int c = 0; c < 8; ++c) {
        const int kc = dbeg + c * 64;
        {
            const ushort* w1p = W1b + (long)(kc + wave * 16 + sr) * 128 + sc * 8;
            #pragma unroll
            for (int s = 0; s < 4; ++s)
                GLL(w1p + s * 32, sW1 + (wave * 4 + s) * 1040);
            #pragma unroll
            for (int gg = 0; gg < 2; ++gg) {
                int cg = wave * 2 + gg;
                const ushort* w2p = W2b + (long)(cg * 16 + sr) * 2048 + kc + sc * 8;
                #pragma unroll
                for (int s2 = 0; s2 < 2; ++s2)
                    GLL(w2p + s2 * 32, sW2 + (cg * 2 + s2) * 1040);
            }
        }
        __syncthreads();

        f32x4 acc1[2][2] = {};
        #pragma unroll
        for (int s = 0; s < 4; ++s) {
            bf16x8 a0 = *(const bf16x8*)(sX + ((xg * 2 + 0) * 4 + s) * 1040 + lane * 16);
            bf16x8 a1 = *(const bf16x8*)(sX + ((xg * 2 + 1) * 4 + s) * 1040 + lane * 16);
            bf16x8 w0 = *(const bf16x8*)(sW1 + ((ch * 2 + 0) * 4 + s) * 1040 + lane * 16);
            bf16x8 w1 = *(const bf16x8*)(sW1 + ((ch * 2 + 1) * 4 + s) * 1040 + lane * 16);
            acc1[0][0] = MFMA16(a0, w0, acc1[0][0]);
            acc1[0][1] = MFMA16(a0, w1, acc1[0][1]);
            acc1[1][0] = MFMA16(a1, w0, acc1[1][0]);
            acc1[1][1] = MFMA16(a1, w1, acc1[1][1]);
        }
        float bb0 = b1[kc + ch * 32 + l16];
        float bb1 = b1[kc + ch * 32 + 16 + l16];
        #pragma unroll
        for (int i = 0; i < 2; ++i) {
            uint8_t* hb = sH + ((xg * 2 + i) * 2 + ch) * 1040;
            #pragma unroll
            for (int j = 0; j < 2; ++j) {
                float bb = j ? bb1 : bb0;
                int q = ((j * 16 + l16) >> 3) & 3;
                int byo = (l16 & 7) * 2;
                #pragma unroll
                for (int r = 0; r < 4; ++r) {
                    float v = fmaxf(acc1[i][j][r] + bb, 0.f);
                    *(ushort*)(hb + q * 256 + (quad * 4 + r) * 16 + byo) = f2b(v);
                }
            }
        }
        __syncthreads();

        #pragma unroll
        for (int s2 = 0; s2 < 2; ++s2) {
            bf16x8 h0 = *(const bf16x8*)(sH + ((xg * 2 + 0) * 2 + s2) * 1040 + lane * 16);
            bf16x8 h1 = *(const bf16x8*)(sH + ((xg * 2 + 1) * 2 + s2) * 1040 + lane * 16);
            #pragma unroll
            for (int j2 = 0; j2 < 4; ++j2) {
                bf16x8 wb = *(const bf16x8*)(sW2 + ((ch * 4 + j2) * 2 + s2) * 1040 + lane * 16);
                acc2[0][j2] = MFMA16(h0, wb, acc2[0][j2]);
                acc2[1][j2] = MFMA16(h1, wb, acc2[1][j2]);
            }
        }
        __syncthreads();
    }

    #pragma unroll
    for (int i = 0; i < 2; ++i)
        #pragma unroll
        for (int r = 0; r < 4; ++r) {
            int row = row0 + xg * 32 + i * 16 + quad * 4 + r;
            #pragma unroll
            for (int j2 = 0; j2 < 4; ++j2) {
                int col = ch * 64 + j2 * 16 + l16;
                atomicAdd(&outf[(long)row * 128 + col], acc2[i][j2][r]);
            }
        }
}

// ---------------------------------------------------------------------------
// Wf_l = Wo_l @ Wv_l (bf16 out),  beff_l = bo_l + Wo_l @ bv_l (fp32)
__global__ __launch_bounds__(256) void fuse_weights(
    const float* __restrict__ Wv0, const float* __restrict__ bv0,
    const float* __restrict__ Wo0, const float* __restrict__ bo0,
    const float* __restrict__ Wv1, const float* __restrict__ bv1,
    const float* __restrict__ Wo1, const float* __restrict__ bo1,
    const float* __restrict__ Wv2, const float* __restrict__ bv2,
    const float* __restrict__ Wo2, const float* __restrict__ bo2,
    ushort* __restrict__ Wfb, float* __restrict__ beff)
{
    int blk = blockIdx.x;
    if (blk >= 192) {
        int l = blk - 192;
        const float* bv = l == 0 ? bv0 : (l == 1 ? bv1 : bv2);
        const float* Wo = l == 0 ? Wo0 : (l == 1 ? Wo1 : Wo2);
        const float* bo = l == 0 ? bo0 : (l == 1 ? bo1 : bo2);
        if (threadIdx.x < 128) {
            int r = threadIdx.x;
            float acc = bo[r];
            #pragma unroll 8
            for (int j = 0; j < 128; ++j) acc += Wo[r * 128 + j] * bv[j];
            beff[l * 128 + r] = acc;
        }
        return;
    }
    int l = blk >> 6;
    const float* Wv = l == 0 ? Wv0 : (l == 1 ? Wv1 : Wv2);
    const float* Wo = l == 0 ? Wo0 : (l == 1 ? Wo1 : Wo2);
    int r = (blk & 63) * 2 + (threadIdx.x >> 7);
    int c = threadIdx.x & 127;
    float acc = 0.f;
    #pragma unroll 8
    for (int j = 0; j < 128; ++j)
        acc += Wo[r * 128 + j] * Wv[j * 128 + c];
    Wfb[l * 16384 + r * 128 + c] = f2b(acc);
}

// ---------------------------------------------------------------------------
// CSR build (merged A/P pipelines via blockIdx.y).
// hist returns the per-edge local offset (wait hidden by TLP); fill is
// atomic-free (slot = off[dst] + local) -- R9, verified -90us.
__global__ void hist2(const int* __restrict__ dA, int* __restrict__ cA, int* __restrict__ lA,
                      const int* __restrict__ dP, int* __restrict__ cP, int* __restrict__ lP,
                      int E)
{
    int e = blockIdx.x * 256 + threadIdx.x;
    if (e >= E) return;
    if (blockIdx.y == 0) lA[e] = atomicAdd(&cA[dA[e]], 1);
    else                 lP[e] = atomicAdd(&cP[dP[e]], 1);
}

__global__ __launch_bounds__(256) void scan_local2(
    const int* __restrict__ inA, int* __restrict__ outA, int* __restrict__ bsumA, int nA,
    const int* __restrict__ inP, int* __restrict__ outP, int* __restrict__ bsumP, int nP)
{
    const int* in  = blockIdx.y ? inP  : inA;
    int* out       = blockIdx.y ? outP : outA;
    int* bsum      = blockIdx.y ? bsumP : bsumA;
    int n          = blockIdx.y ? nP : nA;
    __shared__ int wsum[4];
    int t = threadIdx.x;
    int base = blockIdx.x * 1024 + t * 4;
    int v0 = (base + 0 < n) ? in[base + 0] : 0;
    int v1 = (base + 1 < n) ? in[base + 1] : 0;
    int v2 = (base + 2 < n) ? in[base + 2] : 0;
    int v3 = (base + 3 < n) ? in[base + 3] : 0;
    int tsum = v0 + v1 + v2 + v3;
    int lane = t & 63;
    int x = tsum;
    #pragma unroll
    for (int o = 1; o < 64; o <<= 1) {
        int y = __shfl_up(x, o, 64);
        if (lane >= o) x += y;
    }
    int wid = t >> 6;
    if (lane == 63) wsum[wid] = x;
    __syncthreads();
    int woff = 0;
    #pragma unroll
    for (int ww = 0; ww < 3; ++ww) if (ww < wid) woff += wsum[ww];
    int excl = x - tsum + woff;
    if (base + 0 < n) out[base + 0] = excl;
    if (base + 1 < n) out[base + 1] = excl + v0;
    if (base + 2 < n) out[base + 2] = excl + v0 + v1;
    if (base + 3 < n) out[base + 3] = excl + v0 + v1 + v2;
    if (bsum && t == 255) bsum[blockIdx.x] = excl + tsum;
}

__global__ void scan_add2(int* __restrict__ offA, const int* __restrict__ bA, int nA,
                          int* __restrict__ offP, const int* __restrict__ bP, int nP)
{
    int* off       = blockIdx.y ? offP : offA;
    const int* bofs= blockIdx.y ? bP   : bA;
    int n          = blockIdx.y ? nP : nA;
    int i = blockIdx.x * 256 + threadIdx.x;
    if (i < n) off[i] += bofs[i >> 10];
}

__global__ void fill2(const int* __restrict__ sA, const int* __restrict__ dA,
                      const int* __restrict__ oA, const int* __restrict__ lA,
                      int* __restrict__ eA,
                      const int* __restrict__ sP, const int* __restrict__ dP,
                      const int* __restrict__ oP, const int* __restrict__ lP,
                      int* __restrict__ eP, int E)
{
    int e = blockIdx.x * 256 + threadIdx.x;
    if (e >= E) return;
    if (blockIdx.y == 0) eA[oA[dA[e]] + lA[e]] = sA[e];
    else                 eP[oP[dP[e]] + lP[e]] = sP[e];
}

// ---------------------------------------------------------------------------
// gather + mean only (bf16 in -> bf16 out). One 32-lane group per dst row.
__global__ __launch_bounds__(256) void gather_mean(
    const ushort* __restrict__ z, const int* __restrict__ off,
    const int* __restrict__ cnt, const int* __restrict__ esrc,
    ushort* __restrict__ outh, int R)
{
    int grp = threadIdx.x >> 5;
    int tg  = threadIdx.x & 31;
    int row = blockIdx.x * 8 + grp;
    if (row >= R) return;
    int e0 = off[row], deg = cnt[row];
    int eend = e0 + deg;
    float a0 = 0.f, a1 = 0.f, a2 = 0.f, a3 = 0.f;
    int e = e0;
    for (; e + 4 <= eend; e += 4) {
        int s0 = esrc[e], s1 = esrc[e + 1], s2 = esrc[e + 2], s3 = esrc[e + 3];
        ushort4 v0 = ((const ushort4*)(z + (long)s0 * 128))[tg];
        ushort4 v1 = ((const ushort4*)(z + (long)s1 * 128))[tg];
        ushort4 v2 = ((const ushort4*)(z + (long)s2 * 128))[tg];
        ushort4 v3 = ((const ushort4*)(z + (long)s3 * 128))[tg];
        a0 += b2f(v0.x) + b2f(v1.x) + b2f(v2.x) + b2f(v3.x);
        a1 += b2f(v0.y) + b2f(v1.y) + b2f(v2.y) + b2f(v3.y);
        a2 += b2f(v0.z) + b2f(v1.z) + b2f(v2.z) + b2f(v3.z);
        a3 += b2f(v0.w) + b2f(v1.w) + b2f(v2.w) + b2f(v3.w);
    }
    for (; e < eend; ++e) {
        int s = esrc[e];
        ushort4 v = ((const ushort4*)(z + (long)s * 128))[tg];
        a0 += b2f(v.x); a1 += b2f(v.y); a2 += b2f(v.z); a3 += b2f(v.w);
    }
    float inv = 1.f / fmaxf((float)deg, 1.f);
    ushort4 h4 = {f2b(a0 * inv), f2b(a1 * inv), f2b(a2 * inv), f2b(a3 * inv)};
    ((ushort4*)(outh + (long)row * 128))[tg] = h4;
}

// ---------------------------------------------------------------------------
// Fused gather(bf16) + mean + residual(bf16) + LayerNorm -> bf16 out.
__global__ __launch_bounds__(256) void gather_mean_ln(
    const ushort* __restrict__ z, const int* __restrict__ off,
    const int* __restrict__ cnt, const int* __restrict__ esrc,
    const ushort* __restrict__ base, const float* __restrict__ g,
    const float* __restrict__ b, ushort* __restrict__ outh, int R)
{
    int grp = threadIdx.x >> 5;
    int tg  = threadIdx.x & 31;
    int row = blockIdx.x * 8 + grp;
    if (row >= R) return;
    int e0 = off[row], deg = cnt[row];
    int eend = e0 + deg;
    float a0 = 0.f, a1 = 0.f, a2 = 0.f, a3 = 0.f;
    int e = e0;
    for (; e + 4 <= eend; e += 4) {
        int s0 = esrc[e], s1 = esrc[e + 1], s2 = esrc[e + 2], s3 = esrc[e + 3];
        ushort4 v0 = ((const ushort4*)(z + (long)s0 * 128))[tg];
        ushort4 v1 = ((const ushort4*)(z + (long)s1 * 128))[tg];
        ushort4 v2 = ((const ushort4*)(z + (long)s2 * 128))[tg];
        ushort4 v3 = ((const ushort4*)(z + (long)s3 * 128))[tg];
        a0 += b2f(v0.x) + b2f(v1.x) + b2f(v2.x) + b2f(v3.x);
        a1 += b2f(v0.y) + b2f(v1.y) + b2f(v2.y) + b2f(v3.y);
        a2 += b2f(v0.z) + b2f(v1.z) + b2f(v2.z) + b2f(v3.z);
        a3 += b2f(v0.w) + b2f(v1.w) + b2f(v2.w) + b2f(v3.w);
    }
    for (; e < eend; ++e) {
        int s = esrc[e];
        ushort4 v = ((const ushort4*)(z + (long)s * 128))[tg];
        a0 += b2f(v.x); a1 += b2f(v.y); a2 += b2f(v.z); a3 += b2f(v.w);
    }
    float inv = 1.f / fmaxf((float)deg, 1.f);
    ushort4 bs = ((const ushort4*)(base + (long)row * 128))[tg];
    float x0 = a0 * inv + b2f(bs.x), x1 = a1 * inv + b2f(bs.y);
    float x2 = a2 * inv + b2f(bs.z), x3 = a3 * inv + b2f(bs.w);
    float s1 = x0 + x1 + x2 + x3;
    #pragma unroll
    for (int o = 1; o < 32; o <<= 1) s1 += __shfl_xor(s1, o, 64);
    float mu = s1 * (1.f / 128.f);
    float d0 = x0 - mu, d1 = x1 - mu, d2 = x2 - mu, d3 = x3 - mu;
    float s2 = d0 * d0 + d1 * d1 + d2 * d2 + d3 * d3;
    #pragma unroll
    for (int o = 1; o < 32; o <<= 1) s2 += __shfl_xor(s2, o, 64);
    float rstd = rsqrtf(s2 * (1.f / 128.f) + 1e-5f);
    float4 gv = ((const float4*)g)[tg];
    float4 bv = ((const float4*)b)[tg];
    ushort4 h4;
    h4.x = f2b(d0 * rstd * gv.x + bv.x);
    h4.y = f2b(d1 * rstd * gv.y + bv.y);
    h4.z = f2b(d2 * rstd * gv.z + bv.z);
    h4.w = f2b(d3 * rstd * gv.w + bv.w);
    ((ushort4*)(outh + (long)row * 128))[tg] = h4;
}

// ---------------------------------------------------------------------------
// out = LN(a + bias + base)*g + b ; base either fp32 (basef) or bf16 (baseh).
__global__ __launch_bounds__(128) void mean_add_ln(
    const float* __restrict__ a, const float* __restrict__ bias,
    const float* __restrict__ basef, const ushort* __restrict__ baseh,
    const float* __restrict__ g, const float* __restrict__ b,
    float* __restrict__ outf, ushort* __restrict__ outh, int out_ld, int R)
{
    int row = blockIdx.x;
    if (row >= R) return;
    int d = threadIdx.x;
    float x = a[(long)row * 128 + d];
    if (bias) x += bias[d];
    if (basef) x += basef[(long)row * 128 + d];
    if (baseh) x += b2f(baseh[(long)row * 128 + d]);

    __shared__ float red[4];
    float s = x;
    #pragma unroll
    for (int o = 32; o >= 1; o >>= 1) s += __shfl_xor(s, o, 64);
    if ((d & 63) == 0) red[d >> 6] = s;
    __syncthreads();
    float mu = (red[0] + red[1]) * (1.f / 128.f);
    float dx = x - mu;
    float s2 = dx * dx;
    #pragma unroll
    for (int o = 32; o >= 1; o >>= 1) s2 += __shfl_xor(s2, o, 64);
    if ((d & 63) == 0) red[2 + (d >> 6)] = s2;
    __syncthreads();
    float var = (red[2] + red[3]) * (1.f / 128.f);
    float v = dx * rsqrtf(var + 1e-5f) * g[d] + b[d];
    if (outf) outf[(long)row * out_ld + d] = v;
    if (outh) outh[(long)row * out_ld + d] = f2b(v);
}

// ---------------------------------------------------------------------------
struct CvtArgs { const float* in[6]; ushort* out[6]; int n4[6]; };
__global__ void cvt_multi(CvtArgs a)
{
    int j = blockIdx.y;
    int i = blockIdx.x * 256 + threadIdx.x;
    if (i >= a.n4[j]) return;
    float4 v = ((const float4*)a.in[j])[i];
    ushort4 o;
    o.x = f2b(v.x); o.y = f2b(v.y); o.z = f2b(v.z); o.w = f2b(v.w);
    ((ushort4*)a.out[j])[i] = o;
}

// ---------------------------------------------------------------------------
// Flash attention (split-K=2). R9 exact structure (best measured: 60.7us):
// swizzled sP/sV + register-staged K/V double buffer, one barrier per tile.
// R10/R11 A/B showed GLL-K and ks=4 both regress; reverted.
__global__ __launch_bounds__(256) void flash_attn(
    const ushort* __restrict__ qkvb,
    float* __restrict__ opart, float* __restrict__ lpart_g)
{
    const int qt = blockIdx.x;
    const int mh = blockIdx.y;
    const int ks = blockIdx.z;
    const int m = mh >> 2, h = mh & 3;
    const int wave = threadIdx.x >> 6;
    const int lane = threadIdx.x & 63;
    const int l16 = lane & 15, quad = lane >> 4;

    __shared__ ushort sK[2][64 * 40];
    __shared__ u32    sV[2][32 * 32];
    __shared__ u32    sP[4][16 * 32];

    const int q0 = qt * 64 + wave * 16;
    const float qs = 0.17677669529663687f * 1.4426950408889634f;
    bf16x8 qf;
    {
        bf16x8 qraw = *(const bf16x8*)(qkvb + ((long)(q0 + l16) * 2 + m) * 384 + h * 32 + quad * 8);
        #pragma unroll
        for (int j = 0; j < 8; ++j)
            qf[j] = (short)f2b(b2f((ushort)qraw[j]) * qs);
    }

    f32x4 oacc0 = {0.f, 0.f, 0.f, 0.f};
    f32x4 oacc1 = {0.f, 0.f, 0.f, 0.f};
    float lp = 0.f;

    const int skey = threadIdx.x >> 2, sseg = threadIdx.x & 3;
    const int vkp  = threadIdx.x & 31, vdc  = (threadIdx.x >> 5) * 4;
    const int kbeg = ks * (NA / 2);
    const ushort* kbase = qkvb + ((long)((kbeg + skey) * 2 + m)) * 384 + 128 + h * 32 + sseg * 8;
    const ushort* vbase = qkvb + ((long)((kbeg + vkp * 2) * 2 + m)) * 384 + 256 + h * 32 + vdc;
    const int kwo = skey * 40 + sseg * 8;
    int vwo[4];
    #pragma unroll
    for (int i = 0; i < 4; ++i)
        vwo[i] = (vdc + i) * 32 + ((((vkp >> 2) ^ ((vdc + i) & 7)) << 2) | (vkp & 3));

    bf16x8 kreg = *(const bf16x8*)(kbase);
    ushort4 v0r = *(const ushort4*)(vbase);
    ushort4 v1r = *(const ushort4*)(vbase + 768);
    *(bf16x8*)(&sK[0][kwo]) = kreg;
    sV[0][vwo[0]] = (u32)v0r.x | ((u32)v1r.x << 16);
    sV[0][vwo[1]] = (u32)v0r.y | ((u32)v1r.y << 16);
    sV[0][vwo[2]] = (u32)v0r.z | ((u32)v1r.z << 16);
    sV[0][vwo[3]] = (u32)v0r.w | ((u32)v1r.w << 16);
    __syncthreads();

    int cur = 0;
    for (int kt = 0; kt < 32; ++kt) {
        const bool more = (kt + 1) < 32;
        if (more) {
            long off = (long)(kt + 1) * 64 * 768;
            kreg = *(const bf16x8*)(kbase + off);
            v0r  = *(const ushort4*)(vbase + off);
            v1r  = *(const ushort4*)(vbase + off + 768);
        }

        #pragma unroll
        for (int t = 0; t < 4; ++t) {
            bf16x8 kf = *(const bf16x8*)(&sK[cur][(t * 16 + l16) * 40 + quad * 8]);
            f32x4 s = {0.f, 0.f, 0.f, 0.f};
            s = MFMA16(kf, qf, s);
            float p0 = exp2f(s[0]), p1 = exp2f(s[1]);
            float p2 = exp2f(s[2]), p3 = exp2f(s[3]);
            lp += (p0 + p1) + (p2 + p3);
            u32 lo = __builtin_amdgcn_perm(fbits(p1), fbits(p0), 0x07060302u);
            u32 hi = __builtin_amdgcn_perm(fbits(p3), fbits(p2), 0x07060302u);
            u32* dst = &sP[wave][l16 * 32 +
                                 ((((t * 2 + (quad >> 1)) ^ (l16 & 7)) << 2) | ((quad & 1) * 2))];
            dst[0] = lo; dst[1] = hi;
        }
        #pragma unroll
        for (int c = 0; c < 2; ++c) {
            const int gp = ((c * 4 + quad) ^ (l16 & 7)) << 2;
            bf16x8 pf  = *(const bf16x8*)(&sP[wave][l16 * 32 + gp]);
            bf16x8 vf0 = *(const bf16x8*)(&sV[cur][l16 * 32 + gp]);
            bf16x8 vf1 = *(const bf16x8*)(&sV[cur][(16 + l16) * 32 + gp]);
            oacc0 = MFMA16(pf, vf0, oacc0);
            oacc1 = MFMA16(pf, vf1, oacc1);
        }

        if (more) {
            const int nxt = cur ^ 1;
            *(bf16x8*)(&sK[nxt][kwo]) = kreg;
            sV[nxt][vwo[0]] = (u32)v0r.x | ((u32)v1r.x << 16);
            sV[nxt][vwo[1]] = (u32)v0r.y | ((u32)v1r.y << 16);
            sV[nxt][vwo[2]] = (u32)v0r.z | ((u32)v1r.z << 16);
            sV[nxt][vwo[3]] = (u32)v0r.w | ((u32)v1r.w << 16);
            __syncthreads();
            cur = nxt;
        }
    }

    lp += __shfl_xor(lp, 16, 64);
    lp += __shfl_xor(lp, 32, 64);
    if (quad == 0)
        lpart_g[(long)(mh * 2 + ks) * NA + q0 + l16] = lp;

    #pragma unroll
    for (int r = 0; r < 4; ++r) {
        int qr = q0 + quad * 4 + r;
        long ob = ((long)(mh * 2 + ks) * NA + qr) * 32;
        opart[ob + l16]      = oacc0[r];
        opart[ob + 16 + l16] = oacc1[r];
    }
}

__global__ void attn_combine(const float* __restrict__ opart,
                             const float* __restrict__ lpart,
                             ushort* __restrict__ ctxb)
{
    int idx = blockIdx.x * 256 + threadIdx.x;   // 8*4096*32
    int d = idx & 31;
    int row = idx >> 5;
    int mh = row >> 12, qrow = row & 4095;
    float o = 0.f, l = 0.f;
    #pragma unroll
    for (int ks = 0; ks < 2; ++ks) {
        long rb = (long)(mh * 2 + ks) * NA + qrow;
        o += opart[rb * 32 + d];
        l += lpart[rb];
    }
    int m = mh >> 2, h = mh & 3;
    ctxb[((long)qrow * 2 + m) * 128 + h * 32 + d] = f2b(o / l);
}

// out[a][o] = sum_d 0.5*(x2[2a][d]+x2[2a+1][d]) * Wc[o][d] + bc[o]
__global__ void classify_kernel(const float* __restrict__ x2,
                                const float* __restrict__ Wc,
                                const float* __restrict__ bc,
                                float* __restrict__ out)
{
    int idx = blockIdx.x * 256 + threadIdx.x;
    int a2 = idx >> 4, o = idx & 15;
    const float* r0 = x2 + (long)(a2 * 2) * 128;
    const float* r1 = r0 + 128;
    const float* w = Wc + o * 128;
    float acc = bc[o];
    #pragma unroll 4
    for (int dd = 0; dd < 128; ++dd) acc += 0.5f * (r0[dd] + r1[dd]) * w[dd];
    out[idx] = acc;
}

// ---------------------------------------------------------------------------
static void bgemm(hipStream_t st, const ushort* Abf, const float* Af32, int lda,
                  const ushort* B, int ldb,
                  const float* bias, float* outf, ushort* outh, int ldc,
                  int M, int N, int K, int act = 0, int ksplit = 1)
{
    dim3 grid(N / 128, (M + 63) / 64, ksplit);
    gemm_bf16<<<grid, 256, 0, st>>>(Abf, Af32, lda, B, ldb, bias, outf, outh,
                                    ldc, M, N, K, act);
}

extern "C" void kernel_launch(void* const* d_in, const int* in_sizes, int n_in,
                              void* d_out, int out_size, void* d_ws, size_t ws_size,
                              hipStream_t stream)
{
    const float* x_author = (const float*)d_in[0];
    const float* x_paper  = (const float*)d_in[1];
    const int*   src_ap   = (const int*)d_in[2];
    const int*   dst_ap   = (const int*)d_in[3];
    const int*   src_pa   = (const int*)d_in[4];
    const int*   dst_pa   = (const int*)d_in[5];
    const float* pa_W = (const float*)d_in[6];   const float* pa_b = (const float*)d_in[7];
    const float* pp_W = (const float*)d_in[8];   const float* pp_b = (const float*)d_in[9];
    const float* f_Wqkv = (const float*)d_in[10]; const float* f_bqkv = (const float*)d_in[11];
    const float* f_Wo = (const float*)d_in[12];  const float* f_bo = (const float*)d_in[13];
    const float* f_W1 = (const float*)d_in[14];  const float* f_b1 = (const float*)d_in[15];
    const float* f_W2 = (const float*)d_in[16];  const float* f_b2 = (const float*)d_in[17];
    const float* f_g1 = (const float*)d_in[18];  const float* f_bt1 = (const float*)d_in[19];
    const float* f_g2 = (const float*)d_in[20];  const float* f_bt2 = (const float*)d_in[21];
    const float* cls_W = (const float*)d_in[22]; const float* cls_b = (const float*)d_in[23];
    const float* l0_Wv = (const float*)d_in[24]; const float* l0_bv = (const float*)d_in[25];
    const float* l0_Wo = (const float*)d_in[26]; const float* l0_bo = (const float*)d_in[27];
    const float* l0_g  = (const float*)d_in[28]; const float* l0_b  = (const float*)d_in[29];
    const float* l1_Wv = (const float*)d_in[30]; const float* l1_bv = (const float*)d_in[31];
    const float* l1_Wo = (const float*)d_in[32]; const float* l1_bo = (const float*)d_in[33];
    const float* l1_g  = (const float*)d_in[34]; const float* l1_b  = (const float*)d_in[35];
    const float* l2_Wv = (const float*)d_in[36]; const float* l2_bv = (const float*)d_in[37];
    const float* l2_Wo = (const float*)d_in[38]; const float* l2_bo = (const float*)d_in[39];
    const float* l2_g  = (const float*)d_in[40]; const float* l2_b  = (const float*)d_in[41];

    // ---- workspace carve (bytes), overlays by liveness:
    uint8_t* w = (uint8_t*)d_ws;
    ushort* TB  = (ushort*)(w + 0);            // t bf16 [NP,128] 25.6MB
    float*  OPART = (float*)(w + 26214400);    // attn partials 8MB (ks=2)
    float*  LPART = (float*)(w + 43515904);    // l partials 256KB
    int*   LOC_A  = (int*)(w + 44040192);      // per-edge local offs 2MB (CSR phase)
    int*   LOC_P  = (int*)(w + 46140416);      // 2MB (CSR phase)
    ushort* HPB = (ushort*)(w + 61440000);     // [NP,128] bf16 25.6MB
    ushort* ZB  = (ushort*)(w + 87040000);     // z bf16 [NA,128] 1.05MB
    uint8_t* p2 = w + 102400000;               // phase-2 small tensors
    ushort* QKVB = (ushort*)(p2 + 0);          // [8192,384] bf16 6.29MB
    ushort* CTXB = (ushort*)(p2 + 6291456);    // [8192,128] bf16 2.1MB
    float*  TMP  = (float*)(p2 + 8388608);     // [8192,128] fp32 4.2MB
    float*  X1   = (float*)(p2 + 12582912);    // [8192,128] fp32
    ushort* X1B  = (ushort*)(p2 + 16777216);   // [8192,128] bf16
    float*  TMP2 = (float*)(p2 + 18874368);    // [8192,128] fp32
    float*  X2   = (float*)(p2 + 23068672);    // [8192,128] fp32
    uint8_t* tail = p2 + 27262976;             // persistent
    ushort* STKB  = (ushort*)(tail + 4194304); // [8192,128] bf16 ld 256 layout
    ushort* HAB   = (ushort*)(tail + 6291456); // [NA,128] bf16 1.05MB
    ushort* GMA   = (ushort*)(tail + 7340032); // gathered mean bf16 [NA,128]
    ushort* WFB   = (ushort*)(tail + 8388608); // 3x[128,128] bf16 98KB
    ushort* PAWB  = (ushort*)(tail + 8486912); // [128,128]
    ushort* PPWB  = (ushort*)(tail + 8519680); // [128,256]
    ushort* WQKVB = (ushort*)(tail + 8585216); // [384,128]
    ushort* WOB   = (ushort*)(tail + 8683520); // [128,128]
    ushort* W1B   = (ushort*)(tail + 8716288); // [2048,128]
    ushort* W2B   = (ushort*)(tail + 9240576); // [128,2048]
    float*  BEFF  = (float*)(tail + 9764864);  // 3x[128] fp32
    int*   CNT_A  = (int*)(tail + 9766400);
    int*   OFF_A  = (int*)(tail + 9782784);
    int*   CNT_P  = (int*)(tail + 9815552);
    int*   OFF_P  = (int*)(tail + 10215552);
    int*   ESRC_PA= (int*)(tail + 11015552);
    int*   ESRC_AP= (int*)(tail + 13015552);
    int*   BSUM_A = (int*)(tail + 15015552);
    int*   BSUM_P = (int*)(tail + 15016576);
    float* TMPA   = (float*)(tail + 15017984); // [NA,128] fp32 2.1MB

    // ---- convert weights to bf16 (activations convert in-GEMM)
    CvtArgs ca;
    ca.in[0] = pa_W;   ca.out[0] = PAWB;  ca.n4[0] = D * IN_A / 4;
    ca.in[1] = pp_W;   ca.out[1] = PPWB;  ca.n4[1] = D * IN_P / 4;
    ca.in[2] = f_Wqkv; ca.out[2] = WQKVB; ca.n4[2] = 3 * D * D / 4;
    ca.in[3] = f_Wo;   ca.out[3] = WOB;   ca.n4[3] = D * D / 4;
    ca.in[4] = f_W1;   ca.out[4] = W1B;   ca.n4[4] = DFF * D / 4;
    ca.in[5] = f_W2;   ca.out[5] = W2B;   ca.n4[5] = D * DFF / 4;
    cvt_multi<<<dim3((DFF * D / 4 + 255) / 256, 6), 256, 0, stream>>>(ca);

    fuse_weights<<<195, 256, 0, stream>>>(l0_Wv, l0_bv, l0_Wo, l0_bo,
                                          l1_Wv, l1_bv, l1_Wo, l1_bo,
                                          l2_Wv, l2_bv, l2_Wo, l2_bo, WFB, BEFF);

    // ---- CSR builds, merged A/P pipelines; hist returns per-edge local
    // offset so fill needs no atomic.
    hipMemsetAsync(CNT_A, 0, (size_t)NA * 4, stream);
    hipMemsetAsync(CNT_P, 0, (size_t)NP * 4, stream);
    const int nbA = (NA + 1023) / 1024, nbP = (NP + 1023) / 1024;
    hist2<<<dim3((E_PA + 255) / 256, 2), 256, 0, stream>>>(
        dst_pa, CNT_A, LOC_A, dst_ap, CNT_P, LOC_P, E_PA);
    scan_local2<<<dim3(nbP, 2), 256, 0, stream>>>(CNT_A, OFF_A, BSUM_A, NA,
                                                  CNT_P, OFF_P, BSUM_P, NP);
    scan_local2<<<dim3(1, 2), 256, 0, stream>>>(BSUM_A, BSUM_A, nullptr, nbA,
                                                BSUM_P, BSUM_P, nullptr, nbP);
    scan_add2<<<dim3((NP + 255) / 256, 2), 256, 0, stream>>>(OFF_A, BSUM_A, NA,
                                                             OFF_P, BSUM_P, NP);
    fill2<<<dim3((E_PA + 255) / 256, 2), 256, 0, stream>>>(
        src_pa, dst_pa, OFF_A, LOC_A, ESRC_PA,
        src_ap, dst_ap, OFF_P, LOC_P, ESRC_AP, E_PA);

    // ---- node projections
    bgemm(stream, nullptr, x_author, IN_A, PAWB, IN_A, pa_b, nullptr, HAB, D, NA, D, IN_A);
    bgemm(stream, nullptr, x_paper,  IN_P, PPWB, IN_P, pp_b, nullptr, HPB, D, NP, D, IN_P);

    // ---- metapath 0 (gather-first; K=128 -> bias in-GEMM)
    gather_mean<<<(NA + 7) / 8, 256, 0, stream>>>(HPB, OFF_A, CNT_A, ESRC_PA, GMA, NA);
    bgemm(stream, GMA, nullptr, D, WFB, D, BEFF, TMPA, nullptr, D, NA, D, D);
    mean_add_ln<<<NA, 128, 0, stream>>>(TMPA, nullptr, nullptr, HAB, l0_g, l0_b,
                                        nullptr, STKB, 256, NA);

    // ---- metapath 1 step 1: project (NA rows, cheap), gather into papers
    bgemm(stream, HAB, nullptr, D, WFB + 16384, D, BEFF + 128, nullptr, ZB, D, NA, D, D);
    gather_mean_ln<<<(NP + 7) / 8, 256, 0, stream>>>(
        ZB, OFF_P, CNT_P, ESRC_AP, HPB, l1_g, l1_b, TB, NP);

    // ---- metapath 1 step 2 (gather-first again)
    gather_mean<<<(NA + 7) / 8, 256, 0, stream>>>(TB, OFF_A, CNT_A, ESRC_PA, GMA, NA);
    bgemm(stream, GMA, nullptr, D, WFB + 32768, D, BEFF + 256, TMPA, nullptr, D, NA, D, D);
    mean_add_ln<<<NA, 128, 0, stream>>>(TMPA, nullptr, nullptr, HAB, l2_g, l2_b,
                                        nullptr, STKB + 128, 256, NA);

    // ---- fusion transformer
    bgemm(stream, STKB, nullptr, D, WQKVB, D, f_bqkv, nullptr, QKVB, 3 * D, 2 * NA, 3 * D, D);
    flash_attn<<<dim3(NA / 64, 8, 2), 256, 0, stream>>>(QKVB, OPART, LPART);
    attn_combine<<<8 * NA * 32 / 256, 256, 0, stream>>>(OPART, LPART, CTXB);

    // x1 = LN(stk + ctx@Wo^T + bo): K=128 -> direct with bias in-GEMM
    bgemm(stream, CTXB, nullptr, D, WOB, D, f_bo, TMP, nullptr, D, 2 * NA, D, D);
    mean_add_ln<<<2 * NA, 128, 0, stream>>>(TMP, nullptr, nullptr, STKB, f_g1, f_bt1,
                                            X1, X1B, 128, 2 * NA);

    // FFN fused: x2_pre = relu(x1@W1^T+b1)@W2^T (atomic fp32), then LN
    hipMemsetAsync(TMP2, 0, (size_t)2 * NA * D * 4, stream);
    ffn_fused<<<dim3(2 * NA / 64, 4), 256, 0, stream>>>(X1B, W1B, W2B, f_b1, TMP2);
    mean_add_ln<<<2 * NA, 128, 0, stream>>>(TMP2, f_b2, X1, nullptr, f_g2, f_bt2,
                                            X2, nullptr, 128, 2 * NA);

    // ---- mean over metapaths + classifier (fp32)
    classify_kernel<<<(NA * NOUT) / 256, 256, 0, stream>>>(X2, cls_W, cls_b, (float*)d_out);
}